// Round 3
// baseline (1012.606 us; speedup 1.0000x reference)
//
#include <hip/hip_runtime.h>
#include <cmath>

#define D 128
#define HID 64

__device__ __forceinline__ float silu_f(float x) { return x / (1.0f + expf(-x)); }

__device__ __forceinline__ float4 fma4(float a, float4 w, float4 c) {
    c.x = fmaf(a, w.x, c.x); c.y = fmaf(a, w.y, c.y);
    c.z = fmaf(a, w.z, c.z); c.w = fmaf(a, w.w, c.w);
    return c;
}
__device__ __forceinline__ float4 silu4(float4 v) {
    v.x = silu_f(v.x); v.y = silu_f(v.y); v.z = silu_f(v.z); v.w = silu_f(v.w);
    return v;
}
__device__ __forceinline__ float dot4(float4 a, float4 b) {
    return fmaf(a.x, b.x, fmaf(a.y, b.y, fmaf(a.z, b.z, a.w * b.w)));
}

// order-preserving float <-> uint encode for atomicMax on floats
__device__ __forceinline__ unsigned fenc(float f) {
    unsigned u = __float_as_uint(f);
    return (u & 0x80000000u) ? ~u : (u | 0x80000000u);
}
__device__ __forceinline__ float fdec(unsigned e) {
    unsigned u = (e & 0x80000000u) ? (e & 0x7FFFFFFFu) : ~e;
    return __uint_as_float(u);
}

__global__ void k_copy(const float* __restrict__ src, float* __restrict__ dst, int n4) {
    int i = blockIdx.x * blockDim.x + threadIdx.x;
    if (i < n4) reinterpret_cast<float4*>(dst)[i] = reinterpret_cast<const float4*>(src)[i];
}

// ---- protection net, 4 lanes per node; lane g owns hidden units [g*16, g*16+16) ----
__global__ __launch_bounds__(256) void k_protect(
    const float* __restrict__ states, const float* __restrict__ caps,
    const float* __restrict__ pw1, const float* __restrict__ pb1,
    const float* __restrict__ pw2, const float* __restrict__ pb2,
    unsigned* __restrict__ mask, unsigned* __restrict__ mlist,
    unsigned* __restrict__ counters, float* __restrict__ outmask, int N) {
    unsigned t = blockIdx.x * 256u + threadIdx.x;
    unsigned n = t >> 2, g = t & 3u;
    if (n >= (unsigned)N) return;
    float4 a0, a1, a2, a3;
    { const float4* b4 = reinterpret_cast<const float4*>(pb1) + g * 4;
      a0 = b4[0]; a1 = b4[1]; a2 = b4[2]; a3 = b4[3]; }
    const float4* row = reinterpret_cast<const float4*>(states + (size_t)n * D);
    const float* wbase = pw1 + g * 16;
    for (int kb = 0; kb < 32; ++kb) {
        float4 x = row[kb];
        const float* w = wbase + kb * 4 * HID;
#define PSTEP(xc, off) { const float4* w4 = reinterpret_cast<const float4*>(w + (off) * HID); \
        a0 = fma4(xc, w4[0], a0); a1 = fma4(xc, w4[1], a1); \
        a2 = fma4(xc, w4[2], a2); a3 = fma4(xc, w4[3], a3); }
        PSTEP(x.x, 0) PSTEP(x.y, 1) PSTEP(x.z, 2) PSTEP(x.w, 3)
    }
    {   // capacity = input dim 128
        float xv = caps[n];
        const float* w = wbase + 128 * HID;
        const float4* w4 = reinterpret_cast<const float4*>(w);
        a0 = fma4(xv, w4[0], a0); a1 = fma4(xv, w4[1], a1);
        a2 = fma4(xv, w4[2], a2); a3 = fma4(xv, w4[3], a3);
    }
#undef PSTEP
    // layer 2 partial: serial over this lane's 16 units
    const float* w2 = pw2 + g * 16;
    float p = 0.0f;
    p = fmaf(silu_f(a0.x), w2[0],  p); p = fmaf(silu_f(a0.y), w2[1],  p);
    p = fmaf(silu_f(a0.z), w2[2],  p); p = fmaf(silu_f(a0.w), w2[3],  p);
    p = fmaf(silu_f(a1.x), w2[4],  p); p = fmaf(silu_f(a1.y), w2[5],  p);
    p = fmaf(silu_f(a1.z), w2[6],  p); p = fmaf(silu_f(a1.w), w2[7],  p);
    p = fmaf(silu_f(a2.x), w2[8],  p); p = fmaf(silu_f(a2.y), w2[9],  p);
    p = fmaf(silu_f(a2.z), w2[10], p); p = fmaf(silu_f(a2.w), w2[11], p);
    p = fmaf(silu_f(a3.x), w2[12], p); p = fmaf(silu_f(a3.y), w2[13], p);
    p = fmaf(silu_f(a3.z), w2[14], p); p = fmaf(silu_f(a3.w), w2[15], p);
    p += __shfl_xor(p, 1);
    p += __shfl_xor(p, 2);
    if (g == 0) {
        float act = p + pb2[0];
        unsigned m = (act > 0.0f) ? 1u : 0u;
        mask[n] = m;
        outmask[n] = m ? 1.0f : 0.0f;
        if (m) {
            unsigned slot = atomicAdd(&counters[1], 1u);
            mlist[slot] = n;
        }
    }
}

// compact edges with emask = mask[src] && !mask[tgt]
__global__ void k_compact(const int* __restrict__ ei, const unsigned* __restrict__ mask,
                          unsigned* __restrict__ act_eid, unsigned* __restrict__ counters, int E) {
    int e = blockIdx.x * blockDim.x + threadIdx.x;
    if (e >= E) return;
    int s = ei[e], t = ei[E + e];
    if (mask[s] && !mask[t]) {
        unsigned slot = atomicAdd(&counters[0], 1u);
        act_eid[slot] = (unsigned)e;
    }
}

// ---- redistribution MLP, 4 lanes per active edge ----
__global__ __launch_bounds__(256) void k_edge_mlp(
    const float* __restrict__ states, const int* __restrict__ ei,
    const float* __restrict__ rw1, const float* __restrict__ rb1,
    const float* __restrict__ rw2, const float* __restrict__ rb2,
    const float* __restrict__ rw3, const float* __restrict__ rb3,
    const unsigned* __restrict__ act_eid, const unsigned* __restrict__ counters,
    float* __restrict__ rawbuf, unsigned* __restrict__ segmax, int E) {
    __shared__ float hlds[64][68];            // 64 local groups, padded rows
    unsigned t = blockIdx.x * 256u + threadIdx.x;
    unsigned grp = t >> 2;                    // global active-edge slot
    unsigned g   = t & 3u;                    // quarter id (16 hidden units)
    unsigned gl  = threadIdx.x >> 2;          // local group 0..63
    if (grp >= counters[0]) return;
    int e = (int)act_eid[grp];
    int s = ei[e], tg = ei[E + e];
    const float4* rowA = reinterpret_cast<const float4*>(states + (size_t)s * D);
    const float4* rowB = reinterpret_cast<const float4*>(states + (size_t)tg * D);
    float4 a0, a1, a2, a3;
    { const float4* b4 = reinterpret_cast<const float4*>(rb1) + g * 4;
      a0 = b4[0]; a1 = b4[1]; a2 = b4[2]; a3 = b4[3]; }
    const float* wbase = rw1 + g * 16;
    for (int half = 0; half < 2; ++half) {
        const float4* row = half ? rowB : rowA;
        const float* wb = wbase + half * (D * HID);
        for (int kb = 0; kb < 32; ++kb) {
            float4 x = row[kb];
            const float* w = wb + kb * 4 * HID;
#define ESTEP(xc, off) { const float4* w4 = reinterpret_cast<const float4*>(w + (off) * HID); \
            a0 = fma4(xc, w4[0], a0); a1 = fma4(xc, w4[1], a1); \
            a2 = fma4(xc, w4[2], a2); a3 = fma4(xc, w4[3], a3); }
            ESTEP(x.x, 0) ESTEP(x.y, 1) ESTEP(x.z, 2) ESTEP(x.w, 3)
#undef ESTEP
        }
    }
    a0 = silu4(a0); a1 = silu4(a1); a2 = silu4(a2); a3 = silu4(a3);
    // intra-wave exchange of the 64-unit hidden vector (4 lanes per edge, same wave)
    {
        float4* hrow = reinterpret_cast<float4*>(&hlds[gl][g * 16]);
        hrow[0] = a0; hrow[1] = a1; hrow[2] = a2; hrow[3] = a3;
    }
    // layer 2: this lane computes 16 h2 units
    float4 b0, b1, b2, b3;
    { const float4* b4 = reinterpret_cast<const float4*>(rb2) + g * 4;
      b0 = b4[0]; b1 = b4[1]; b2 = b4[2]; b3 = b4[3]; }
    const float4* hr4 = reinterpret_cast<const float4*>(&hlds[gl][0]);
    const float* w2base = rw2 + g * 16;
    for (int kb = 0; kb < 16; ++kb) {
        float4 hh = hr4[kb];
        const float* w = w2base + (kb * 4) * HID;
#define ESTEP2(hc, off) { const float4* w4 = reinterpret_cast<const float4*>(w + (off) * HID); \
        b0 = fma4(hc, w4[0], b0); b1 = fma4(hc, w4[1], b1); \
        b2 = fma4(hc, w4[2], b2); b3 = fma4(hc, w4[3], b3); }
        ESTEP2(hh.x, 0) ESTEP2(hh.y, 1) ESTEP2(hh.z, 2) ESTEP2(hh.w, 3)
#undef ESTEP2
    }
    b0 = silu4(b0); b1 = silu4(b1); b2 = silu4(b2); b3 = silu4(b3);
    // layer 3: per-lane partial dot, then group reduce
    const float4* w3 = reinterpret_cast<const float4*>(rw3 + g * 16);
    float p = (dot4(b0, w3[0]) + dot4(b1, w3[1])) + (dot4(b2, w3[2]) + dot4(b3, w3[3]));
    p += __shfl_xor(p, 1);
    p += __shfl_xor(p, 2);
    if (g == 0) {
        float raw = p + rb3[0];
        rawbuf[grp] = raw;
        atomicMax(&segmax[s], fenc(raw));
    }
}

__global__ void k_exp(const int* __restrict__ ei, const unsigned* __restrict__ act_eid,
                      const unsigned* __restrict__ counters, const unsigned* __restrict__ segmax,
                      float* __restrict__ rawbuf, float* __restrict__ denom, int E) {
    unsigned t = blockIdx.x * blockDim.x + threadIdx.x;
    if (t >= counters[0]) return;
    int e = (int)act_eid[t];
    int s = ei[e];
    float ev = expf(rawbuf[t] - fdec(segmax[s]));
    rawbuf[t] = ev;
    atomicAdd(&denom[s], ev);
}

// wave-per-active-edge: out[tgt] += w * states[src]
__global__ __launch_bounds__(256) void k_scatter(
    const float* __restrict__ states, const int* __restrict__ ei,
    const unsigned* __restrict__ act_eid, const unsigned* __restrict__ counters,
    const float* __restrict__ rawbuf, const float* __restrict__ denom,
    float* __restrict__ out, int E) {
    unsigned w = blockIdx.x * (blockDim.x >> 6) + (threadIdx.x >> 6);
    unsigned lane = threadIdx.x & 63u;
    if (w >= counters[0]) return;
    int e = (int)act_eid[w];
    int s = ei[e], tg = ei[E + e];
    float wt = rawbuf[w] / denom[s];
    const float* srow = states + (size_t)s * D;
    float* orow = out + (size_t)tg * D;
    atomicAdd(&orow[lane], wt * srow[lane]);
    atomicAdd(&orow[lane + 64], wt * srow[lane + 64]);
}

// failed nodes: out = tanh(redist @ tw + tb) * 0.05
// 2 nodes per 256-thread block; thread-per-(node,dim); LDS-staged input row
__global__ __launch_bounds__(256) void k_jump(
    const float* __restrict__ tw, const float* __restrict__ tb,
    const unsigned* __restrict__ mlist, const unsigned* __restrict__ counters,
    float* __restrict__ out) {
    __shared__ float xs[2][D];
    unsigned g = threadIdx.x >> 7;
    unsigned d = threadIdx.x & 127u;
    unsigned slot = blockIdx.x * 2 + g;
    bool valid = slot < counters[1];
    int n = valid ? (int)mlist[slot] : 0;
    float* row = out + (size_t)n * D;
    if (valid) xs[g][d] = row[d];
    __syncthreads();
    if (!valid) return;
    float acc = tb[d];
    const float* ws = &xs[g][0];
    for (int k = 0; k < D; k += 4) {
        acc = fmaf(ws[k + 0], tw[(k + 0) * D + d], acc);
        acc = fmaf(ws[k + 1], tw[(k + 1) * D + d], acc);
        acc = fmaf(ws[k + 2], tw[(k + 2) * D + d], acc);
        acc = fmaf(ws[k + 3], tw[(k + 3) * D + d], acc);
    }
    row[d] = tanhf(acc) * 0.05f;
}

extern "C" void kernel_launch(void* const* d_in, const int* in_sizes, int n_in,
                              void* d_out, int out_size, void* d_ws, size_t ws_size,
                              hipStream_t stream) {
    const float* states = (const float*)d_in[0];
    const float* caps   = (const float*)d_in[1];
    const int*   ei     = (const int*)d_in[2];
    const float* rw1 = (const float*)d_in[3];  const float* rb1 = (const float*)d_in[4];
    const float* rw2 = (const float*)d_in[5];  const float* rb2 = (const float*)d_in[6];
    const float* rw3 = (const float*)d_in[7];  const float* rb3 = (const float*)d_in[8];
    const float* pw1 = (const float*)d_in[9];  const float* pb1 = (const float*)d_in[10];
    const float* pw2 = (const float*)d_in[11]; const float* pb2 = (const float*)d_in[12];
    const float* tw  = (const float*)d_in[13]; const float* tb  = (const float*)d_in[14];
    const int N = in_sizes[1];
    const int E = in_sizes[2] / 2;
    float* out = (float*)d_out;

    // ws layout (u32 units): [0..3] counters | segmax N | denom N | mask N | mlist N | act_eid E | rawbuf E
    unsigned* ws       = (unsigned*)d_ws;
    unsigned* counters = ws;
    unsigned* segmax   = ws + 4;
    float*    denom    = (float*)(ws + 4 + (size_t)N);
    unsigned* mask     = ws + 4 + 2 * (size_t)N;
    unsigned* mlist    = ws + 4 + 3 * (size_t)N;
    unsigned* act_eid  = ws + 4 + 4 * (size_t)N;
    float*    rawbuf   = (float*)(ws + 4 + 4 * (size_t)N + (size_t)E);

    hipMemsetAsync(d_ws, 0, (size_t)(4 + 2 * (size_t)N) * 4, stream);

    const int n4 = N * D / 4;
    k_copy<<<(n4 + 255) / 256, 256, 0, stream>>>(states, out, n4);
    k_protect<<<(4 * N + 255) / 256, 256, 0, stream>>>(states, caps, pw1, pb1, pw2, pb2,
                                                       mask, mlist, counters, out + (size_t)N * D, N);
    k_compact<<<(E + 255) / 256, 256, 0, stream>>>(ei, mask, act_eid, counters, E);
    k_edge_mlp<<<(4 * E + 255) / 256, 256, 0, stream>>>(states, ei, rw1, rb1, rw2, rb2, rw3, rb3,
                                                        act_eid, counters, rawbuf, segmax, E);
    k_exp<<<(E + 255) / 256, 256, 0, stream>>>(ei, act_eid, counters, segmax, rawbuf, denom, E);
    k_scatter<<<(E + 3) / 4, 256, 0, stream>>>(states, ei, act_eid, counters, rawbuf, denom, out, E);
    k_jump<<<(N + 1) / 2, 256, 0, stream>>>(tw, tb, mlist, counters, out);
}

// Round 4
// 889.804 us; speedup vs baseline: 1.1380x; 1.1380x over previous
//
#include <hip/hip_runtime.h>
#include <cmath>

#define D 128
#define HID 64

typedef _Float16 h2v __attribute__((ext_vector_type(2)));

__device__ __forceinline__ float silu_f(float x) { return x / (1.0f + expf(-x)); }

__device__ __forceinline__ float4 fma4(float a, float4 w, float4 c) {
    c.x = fmaf(a, w.x, c.x); c.y = fmaf(a, w.y, c.y);
    c.z = fmaf(a, w.z, c.z); c.w = fmaf(a, w.w, c.w);
    return c;
}
__device__ __forceinline__ float4 silu4(float4 v) {
    v.x = silu_f(v.x); v.y = silu_f(v.y); v.z = silu_f(v.z); v.w = silu_f(v.w);
    return v;
}
__device__ __forceinline__ float dot4(float4 a, float4 b) {
    return fmaf(a.x, b.x, fmaf(a.y, b.y, fmaf(a.z, b.z, a.w * b.w)));
}

// f32 pair -> packed f16x2 (RNE)
__device__ __forceinline__ unsigned packf2(float a, float b) {
    unsigned short ua = __builtin_bit_cast(unsigned short, (_Float16)a);
    unsigned short ub = __builtin_bit_cast(unsigned short, (_Float16)b);
    return (unsigned)ua | ((unsigned)ub << 16);
}

// dot2: c += a.lo*b.lo + a.hi*b.hi  (v_dot2_f32_f16)
__device__ __forceinline__ float hdot2(unsigned a, unsigned b, float c) {
#if __has_builtin(__builtin_amdgcn_fdot2)
    return __builtin_amdgcn_fdot2(__builtin_bit_cast(h2v, a), __builtin_bit_cast(h2v, b), c, false);
#else
    h2v av = __builtin_bit_cast(h2v, a), bv = __builtin_bit_cast(h2v, b);
    return fmaf((float)av.y, (float)bv.y, fmaf((float)av.x, (float)bv.x, c));
#endif
}

// order-preserving float <-> uint encode for atomicMax on floats
__device__ __forceinline__ unsigned fenc(float f) {
    unsigned u = __float_as_uint(f);
    return (u & 0x80000000u) ? ~u : (u | 0x80000000u);
}
__device__ __forceinline__ float fdec(unsigned e) {
    unsigned u = (e & 0x80000000u) ? (e & 0x7FFFFFFFu) : ~e;
    return __uint_as_float(u);
}

__global__ void k_copy(const float* __restrict__ src, float* __restrict__ dst, int n4) {
    int i = blockIdx.x * blockDim.x + threadIdx.x;
    if (i < n4) reinterpret_cast<float4*>(dst)[i] = reinterpret_cast<const float4*>(src)[i];
}

// pack rw1 (256x64 f32, k-major rows) -> rw1p[kp][u] = f16x2(rw1[2kp][u], rw1[2kp+1][u])
__global__ void k_prep1(const float* __restrict__ rw1, unsigned* __restrict__ rw1p) {
    int i = blockIdx.x * blockDim.x + threadIdx.x;
    if (i >= 128 * HID) return;
    int kp = i >> 6, u = i & 63;
    rw1p[i] = packf2(rw1[(2 * kp) * HID + u], rw1[(2 * kp + 1) * HID + u]);
}

// ---- protection net: 4 lanes per node, split-K (f32 for mask stability) ----
__global__ __launch_bounds__(256) void k_protect(
    const float* __restrict__ states, const float* __restrict__ caps,
    const float* __restrict__ pw1, const float* __restrict__ pb1,
    const float* __restrict__ pw2, const float* __restrict__ pb2,
    unsigned* __restrict__ mask, unsigned* __restrict__ mlist,
    unsigned* __restrict__ counters, float* __restrict__ outmask, int N) {
    unsigned t = blockIdx.x * 256u + threadIdx.x;
    unsigned n = t >> 2, p = t & 3u;
    if (n >= (unsigned)N) return;
    float bs = (p == 0) ? 1.0f : 0.0f;
    float4 h0, h1, h2, h3, h4, h5, h6, h7, h8, h9, h10, h11, h12, h13, h14, h15;
    { const float4* b4 = reinterpret_cast<const float4*>(pb1);
      h0 = b4[0]; h1 = b4[1]; h2 = b4[2]; h3 = b4[3];
      h4 = b4[4]; h5 = b4[5]; h6 = b4[6]; h7 = b4[7];
      h8 = b4[8]; h9 = b4[9]; h10 = b4[10]; h11 = b4[11];
      h12 = b4[12]; h13 = b4[13]; h14 = b4[14]; h15 = b4[15];
#define SCL(v) v.x *= bs; v.y *= bs; v.z *= bs; v.w *= bs;
      SCL(h0) SCL(h1) SCL(h2) SCL(h3) SCL(h4) SCL(h5) SCL(h6) SCL(h7)
      SCL(h8) SCL(h9) SCL(h10) SCL(h11) SCL(h12) SCL(h13) SCL(h14) SCL(h15)
#undef SCL
    }
#define ACC16(xv, wp) { const float4* _w4 = reinterpret_cast<const float4*>(wp); \
    h0  = fma4(xv, _w4[0],  h0);  h1  = fma4(xv, _w4[1],  h1);  \
    h2  = fma4(xv, _w4[2],  h2);  h3  = fma4(xv, _w4[3],  h3);  \
    h4  = fma4(xv, _w4[4],  h4);  h5  = fma4(xv, _w4[5],  h5);  \
    h6  = fma4(xv, _w4[6],  h6);  h7  = fma4(xv, _w4[7],  h7);  \
    h8  = fma4(xv, _w4[8],  h8);  h9  = fma4(xv, _w4[9],  h9);  \
    h10 = fma4(xv, _w4[10], h10); h11 = fma4(xv, _w4[11], h11); \
    h12 = fma4(xv, _w4[12], h12); h13 = fma4(xv, _w4[13], h13); \
    h14 = fma4(xv, _w4[14], h14); h15 = fma4(xv, _w4[15], h15); }
    // this lane's k-quarter: dims [32p, 32p+32)
    const float4* row = reinterpret_cast<const float4*>(states + (size_t)n * D + p * 32);
    const float* wq = pw1 + (p * 32) * HID;
#pragma unroll 1
    for (int i = 0; i < 8; ++i) {
        float4 x = row[i];
        const float* w = wq + i * 4 * HID;
        ACC16(x.x, w) ACC16(x.y, w + HID) ACC16(x.z, w + 2 * HID) ACC16(x.w, w + 3 * HID)
    }
    {   // capacity row (dim 128): only lane 3 contributes a nonzero x
        float xv = (p == 3) ? caps[n] : 0.0f;
        ACC16(xv, pw1 + 128 * HID)
    }
#undef ACC16
    // butterfly: all 4 lanes end with the full h (incl. bias)
#define XCH(v, m) { v.x += __shfl_xor(v.x, m); v.y += __shfl_xor(v.y, m); \
                    v.z += __shfl_xor(v.z, m); v.w += __shfl_xor(v.w, m); }
#define XCHALL(m) XCH(h0,m) XCH(h1,m) XCH(h2,m) XCH(h3,m) XCH(h4,m) XCH(h5,m) XCH(h6,m) XCH(h7,m) \
                  XCH(h8,m) XCH(h9,m) XCH(h10,m) XCH(h11,m) XCH(h12,m) XCH(h13,m) XCH(h14,m) XCH(h15,m)
    XCHALL(1)
    XCHALL(2)
#undef XCHALL
    // layer 2: serial silu-dot over all 64 units (redundant on all 4 lanes)
    const float4* w2 = reinterpret_cast<const float4*>(pw2);
    float act = pb2[0];
#define AD(hh, ww) { float4 _w = ww; \
    act = fmaf(silu_f(hh.x), _w.x, act); act = fmaf(silu_f(hh.y), _w.y, act); \
    act = fmaf(silu_f(hh.z), _w.z, act); act = fmaf(silu_f(hh.w), _w.w, act); }
    AD(h0, w2[0])  AD(h1, w2[1])  AD(h2, w2[2])  AD(h3, w2[3])
    AD(h4, w2[4])  AD(h5, w2[5])  AD(h6, w2[6])  AD(h7, w2[7])
    AD(h8, w2[8])  AD(h9, w2[9])  AD(h10, w2[10]) AD(h11, w2[11])
    AD(h12, w2[12]) AD(h13, w2[13]) AD(h14, w2[14]) AD(h15, w2[15])
#undef AD
    if (p == 0) {
        unsigned m = (act > 0.0f) ? 1u : 0u;
        mask[n] = m;
        outmask[n] = m ? 1.0f : 0.0f;
        if (m) {
            unsigned slot = atomicAdd(&counters[1], 1u);
            mlist[slot] = n;
        }
    }
}

// compact edges with emask = mask[src] && !mask[tgt]
__global__ void k_compact(const int* __restrict__ ei, const unsigned* __restrict__ mask,
                          unsigned* __restrict__ act_eid, unsigned* __restrict__ counters, int E) {
    int e = blockIdx.x * blockDim.x + threadIdx.x;
    if (e >= E) return;
    int s = ei[e], t = ei[E + e];
    if (mask[s] && !mask[t]) {
        unsigned slot = atomicAdd(&counters[0], 1u);
        act_eid[slot] = (unsigned)e;
    }
}

// ---- redistribution MLP: 2 lanes per active edge, split-K; layer1 f16-dot2 ----
__global__ __launch_bounds__(256) void k_edge_mlp(
    const float* __restrict__ states, const int* __restrict__ ei,
    const unsigned* __restrict__ rw1p, const float* __restrict__ rb1,
    const float* __restrict__ rw2, const float* __restrict__ rb2,
    const float* __restrict__ rw3, const float* __restrict__ rb3,
    const unsigned* __restrict__ act_eid, const unsigned* __restrict__ counters,
    float* __restrict__ rawbuf, unsigned* __restrict__ segmax, int E) {
    unsigned t = blockIdx.x * 256u + threadIdx.x;
    unsigned grp = t >> 1, p = t & 1u;
    if (grp >= counters[0]) return;
    int e = (int)act_eid[grp];
    int s = ei[e], tg = ei[E + e];
    // lane p gathers one row: p=0 -> src, p=1 -> tgt (k-pairs [64p, 64p+64))
    const float4* row = reinterpret_cast<const float4*>(states + (size_t)(p ? tg : s) * D);
    float bs = (p == 0) ? 1.0f : 0.0f;
    float4 h0, h1, h2, h3, h4, h5, h6, h7, h8, h9, h10, h11, h12, h13, h14, h15;
    { const float4* b4 = reinterpret_cast<const float4*>(rb1);
      h0 = b4[0]; h1 = b4[1]; h2 = b4[2]; h3 = b4[3];
      h4 = b4[4]; h5 = b4[5]; h6 = b4[6]; h7 = b4[7];
      h8 = b4[8]; h9 = b4[9]; h10 = b4[10]; h11 = b4[11];
      h12 = b4[12]; h13 = b4[13]; h14 = b4[14]; h15 = b4[15];
#define SCL(v) v.x *= bs; v.y *= bs; v.z *= bs; v.w *= bs;
      SCL(h0) SCL(h1) SCL(h2) SCL(h3) SCL(h4) SCL(h5) SCL(h6) SCL(h7)
      SCL(h8) SCL(h9) SCL(h10) SCL(h11) SCL(h12) SCL(h13) SCL(h14) SCL(h15)
#undef SCL
    }
#define DOTQ(hh, ww, xp) { hh.x = hdot2(xp, ww.x, hh.x); hh.y = hdot2(xp, ww.y, hh.y); \
                           hh.z = hdot2(xp, ww.z, hh.z); hh.w = hdot2(xp, ww.w, hh.w); }
#define DOT64(xp, wptr) { const uint4* _w = reinterpret_cast<const uint4*>(wptr); \
    DOTQ(h0,  _w[0],  xp) DOTQ(h1,  _w[1],  xp) DOTQ(h2,  _w[2],  xp) DOTQ(h3,  _w[3],  xp) \
    DOTQ(h4,  _w[4],  xp) DOTQ(h5,  _w[5],  xp) DOTQ(h6,  _w[6],  xp) DOTQ(h7,  _w[7],  xp) \
    DOTQ(h8,  _w[8],  xp) DOTQ(h9,  _w[9],  xp) DOTQ(h10, _w[10], xp) DOTQ(h11, _w[11], xp) \
    DOTQ(h12, _w[12], xp) DOTQ(h13, _w[13], xp) DOTQ(h14, _w[14], xp) DOTQ(h15, _w[15], xp) }
    const unsigned* wbase = rw1p + (size_t)p * 64 * HID;   // this lane's 64 k-pairs
#pragma unroll 1
    for (int i = 0; i < 16; ++i) {
        float4 xa = row[2 * i], xb = row[2 * i + 1];
        unsigned xp0 = packf2(xa.x, xa.y);
        unsigned xp1 = packf2(xa.z, xa.w);
        unsigned xp2 = packf2(xb.x, xb.y);
        unsigned xp3 = packf2(xb.z, xb.w);
        const unsigned* w = wbase + (size_t)(4 * i) * HID;
        DOT64(xp0, w) DOT64(xp1, w + HID) DOT64(xp2, w + 2 * HID) DOT64(xp3, w + 3 * HID)
    }
#undef DOT64
#undef DOTQ
    // exchange partial h across the lane pair -> both lanes hold full h
#define XCH1(v) { v.x += __shfl_xor(v.x, 1); v.y += __shfl_xor(v.y, 1); \
                  v.z += __shfl_xor(v.z, 1); v.w += __shfl_xor(v.w, 1); }
    XCH1(h0) XCH1(h1) XCH1(h2) XCH1(h3) XCH1(h4) XCH1(h5) XCH1(h6) XCH1(h7)
    XCH1(h8) XCH1(h9) XCH1(h10) XCH1(h11) XCH1(h12) XCH1(h13) XCH1(h14) XCH1(h15)
    h0 = silu4(h0); h1 = silu4(h1); h2 = silu4(h2); h3 = silu4(h3);
    h4 = silu4(h4); h5 = silu4(h5); h6 = silu4(h6); h7 = silu4(h7);
    h8 = silu4(h8); h9 = silu4(h9); h10 = silu4(h10); h11 = silu4(h11);
    h12 = silu4(h12); h13 = silu4(h13); h14 = silu4(h14); h15 = silu4(h15);
    // layer 2 (f32): lane p computes h2 units j in [32p, 32p+32)
    float4 b0, b1, b2, b3, b4, b5, b6, b7;
    { const float4* bb = reinterpret_cast<const float4*>(rb2) + p * 8;
      b0 = bb[0]; b1 = bb[1]; b2 = bb[2]; b3 = bb[3];
      b4 = bb[4]; b5 = bb[5]; b6 = bb[6]; b7 = bb[7]; }
#define L2STEP(hc, k) { const float4* _w = reinterpret_cast<const float4*>(rw2 + (size_t)(k) * HID) + p * 8; \
    b0 = fma4(hc, _w[0], b0); b1 = fma4(hc, _w[1], b1); b2 = fma4(hc, _w[2], b2); b3 = fma4(hc, _w[3], b3); \
    b4 = fma4(hc, _w[4], b4); b5 = fma4(hc, _w[5], b5); b6 = fma4(hc, _w[6], b6); b7 = fma4(hc, _w[7], b7); }
#define L2G(hr, kb) L2STEP(hr.x, kb) L2STEP(hr.y, (kb)+1) L2STEP(hr.z, (kb)+2) L2STEP(hr.w, (kb)+3)
    L2G(h0, 0)   L2G(h1, 4)   L2G(h2, 8)   L2G(h3, 12)
    L2G(h4, 16)  L2G(h5, 20)  L2G(h6, 24)  L2G(h7, 28)
    L2G(h8, 32)  L2G(h9, 36)  L2G(h10, 40) L2G(h11, 44)
    L2G(h12, 48) L2G(h13, 52) L2G(h14, 56) L2G(h15, 60)
#undef L2G
#undef L2STEP
    b0 = silu4(b0); b1 = silu4(b1); b2 = silu4(b2); b3 = silu4(b3);
    b4 = silu4(b4); b5 = silu4(b5); b6 = silu4(b6); b7 = silu4(b7);
    // layer 3: partial dot over this lane's 32 units, then pair-reduce
    const float4* w3 = reinterpret_cast<const float4*>(rw3) + p * 8;
    float part = ((dot4(b0, w3[0]) + dot4(b1, w3[1])) + (dot4(b2, w3[2]) + dot4(b3, w3[3])))
               + ((dot4(b4, w3[4]) + dot4(b5, w3[5])) + (dot4(b6, w3[6]) + dot4(b7, w3[7])));
    part += __shfl_xor(part, 1);
    if (p == 0) {
        float raw = part + rb3[0];
        rawbuf[grp] = raw;
        atomicMax(&segmax[s], fenc(raw));
    }
}

__global__ void k_exp(const int* __restrict__ ei, const unsigned* __restrict__ act_eid,
                      const unsigned* __restrict__ counters, const unsigned* __restrict__ segmax,
                      float* __restrict__ rawbuf, float* __restrict__ denom, int E) {
    unsigned t = blockIdx.x * blockDim.x + threadIdx.x;
    if (t >= counters[0]) return;
    int e = (int)act_eid[t];
    int s = ei[e];
    float ev = expf(rawbuf[t] - fdec(segmax[s]));
    rawbuf[t] = ev;
    atomicAdd(&denom[s], ev);
}

// wave-per-active-edge: out[tgt] += w * states[src]
__global__ __launch_bounds__(256) void k_scatter(
    const float* __restrict__ states, const int* __restrict__ ei,
    const unsigned* __restrict__ act_eid, const unsigned* __restrict__ counters,
    const float* __restrict__ rawbuf, const float* __restrict__ denom,
    float* __restrict__ out, int E) {
    unsigned w = blockIdx.x * (blockDim.x >> 6) + (threadIdx.x >> 6);
    unsigned lane = threadIdx.x & 63u;
    if (w >= counters[0]) return;
    int e = (int)act_eid[w];
    int s = ei[e], tg = ei[E + e];
    float wt = rawbuf[w] / denom[s];
    const float* srow = states + (size_t)s * D;
    float* orow = out + (size_t)tg * D;
    atomicAdd(&orow[lane], wt * srow[lane]);
    atomicAdd(&orow[lane + 64], wt * srow[lane + 64]);
}

// failed nodes: out = tanh(redist @ tw + tb) * 0.05
__global__ __launch_bounds__(256) void k_jump(
    const float* __restrict__ tw, const float* __restrict__ tb,
    const unsigned* __restrict__ mlist, const unsigned* __restrict__ counters,
    float* __restrict__ out) {
    __shared__ float xs[2][D];
    unsigned g = threadIdx.x >> 7;
    unsigned d = threadIdx.x & 127u;
    unsigned slot = blockIdx.x * 2 + g;
    bool valid = slot < counters[1];
    int n = valid ? (int)mlist[slot] : 0;
    float* row = out + (size_t)n * D;
    if (valid) xs[g][d] = row[d];
    __syncthreads();
    if (!valid) return;
    float acc = tb[d];
    const float* ws = &xs[g][0];
    for (int k = 0; k < D; k += 4) {
        acc = fmaf(ws[k + 0], tw[(k + 0) * D + d], acc);
        acc = fmaf(ws[k + 1], tw[(k + 1) * D + d], acc);
        acc = fmaf(ws[k + 2], tw[(k + 2) * D + d], acc);
        acc = fmaf(ws[k + 3], tw[(k + 3) * D + d], acc);
    }
    row[d] = tanhf(acc) * 0.05f;
}

extern "C" void kernel_launch(void* const* d_in, const int* in_sizes, int n_in,
                              void* d_out, int out_size, void* d_ws, size_t ws_size,
                              hipStream_t stream) {
    const float* states = (const float*)d_in[0];
    const float* caps   = (const float*)d_in[1];
    const int*   ei     = (const int*)d_in[2];
    const float* rw1 = (const float*)d_in[3];  const float* rb1 = (const float*)d_in[4];
    const float* rw2 = (const float*)d_in[5];  const float* rb2 = (const float*)d_in[6];
    const float* rw3 = (const float*)d_in[7];  const float* rb3 = (const float*)d_in[8];
    const float* pw1 = (const float*)d_in[9];  const float* pb1 = (const float*)d_in[10];
    const float* pw2 = (const float*)d_in[11]; const float* pb2 = (const float*)d_in[12];
    const float* tw  = (const float*)d_in[13]; const float* tb  = (const float*)d_in[14];
    const int N = in_sizes[1];
    const int E = in_sizes[2] / 2;
    float* out = (float*)d_out;

    // ws layout (u32 units): [0..3] counters | segmax N | denom N | mask N | mlist N | act_eid E | rawbuf E | rw1p 8192
    unsigned* ws       = (unsigned*)d_ws;
    unsigned* counters = ws;
    unsigned* segmax   = ws + 4;
    float*    denom    = (float*)(ws + 4 + (size_t)N);
    unsigned* mask     = ws + 4 + 2 * (size_t)N;
    unsigned* mlist    = ws + 4 + 3 * (size_t)N;
    unsigned* act_eid  = ws + 4 + 4 * (size_t)N;
    float*    rawbuf   = (float*)(ws + 4 + 4 * (size_t)N + (size_t)E);
    unsigned* rw1p     = ws + 4 + 4 * (size_t)N + 2 * (size_t)E;

    hipMemsetAsync(d_ws, 0, (size_t)(4 + 2 * (size_t)N) * 4, stream);

    k_prep1<<<(128 * HID + 255) / 256, 256, 0, stream>>>(rw1, rw1p);
    const int n4 = N * D / 4;
    k_copy<<<(n4 + 255) / 256, 256, 0, stream>>>(states, out, n4);
    k_protect<<<(4 * N + 255) / 256, 256, 0, stream>>>(states, caps, pw1, pb1, pw2, pb2,
                                                       mask, mlist, counters, out + (size_t)N * D, N);
    k_compact<<<(E + 255) / 256, 256, 0, stream>>>(ei, mask, act_eid, counters, E);
    k_edge_mlp<<<(2 * E + 255) / 256, 256, 0, stream>>>(states, ei, rw1p, rb1, rw2, rb2, rw3, rb3,
                                                        act_eid, counters, rawbuf, segmax, E);
    k_exp<<<(E + 255) / 256, 256, 0, stream>>>(ei, act_eid, counters, segmax, rawbuf, denom, E);
    k_scatter<<<(E + 3) / 4, 256, 0, stream>>>(states, ei, act_eid, counters, rawbuf, denom, out, E);
    k_jump<<<(N + 1) / 2, 256, 0, stream>>>(tw, tb, mlist, counters, out);
}